// Round 1
// baseline (5244.678 us; speedup 1.0000x reference)
//
#include <hip/hip_runtime.h>
#include <math.h>

#define CDIV(a,b) (((a)+(b)-1)/(b))

// ---------------------------------------------------------------- helpers
static __device__ __forceinline__ float gelu_exact(float x) {
    // jax.nn.gelu(approximate=False) = 0.5 x (1 + erf(x/sqrt(2)))
    return 0.5f * x * (1.0f + erff(x * 0.7071067811865475f));
}

// blockDim must be 256 (4 waves). sbuf must hold >=4 floats.
static __device__ __forceinline__ float block_sum_256(float v, float* sbuf) {
    #pragma unroll
    for (int off = 32; off; off >>= 1) v += __shfl_down(v, off, 64);
    const int lane = threadIdx.x & 63;
    const int wid  = threadIdx.x >> 6;
    __syncthreads();               // protect sbuf reuse across calls
    if (lane == 0) sbuf[wid] = v;
    __syncthreads();
    return sbuf[0] + sbuf[1] + sbuf[2] + sbuf[3];
}

// ---------------------------------------------------------------- SGEMM
// C[M,N] = epilogue(A[M,K] @ W[N,K]^T + bias) * scale
// BM=BN=128, BK=8, 256 threads, 8x8 per thread. M % 128 == 0, K % 8 == 0.
// N arbitrary (bounds-checked on W loads and C stores).
template<bool GELU>
__global__ __launch_bounds__(256)
void sgemm_kernel(const float* __restrict__ A, const float* __restrict__ W,
                  const float* __restrict__ bias, float* __restrict__ C,
                  int M, int N, int K, float scale)
{
    __shared__ float As[8][128];
    __shared__ float Ws[8][128];

    const int tid  = threadIdx.x;
    const int row0 = blockIdx.y * 128;
    const int col0 = blockIdx.x * 128;

    // staging: each thread loads one float4 of A and one of W per K-step
    const int lr = tid >> 1;             // 0..127 (row within tile)
    const int lk = (tid & 1) * 4;        // 0 or 4 (k within tile)
    const float* Aptr = A + (size_t)(row0 + lr) * K + lk;
    const int    wrow = col0 + lr;
    const float* Wptr = W + (size_t)wrow * K + lk;
    const bool   wvalid = (wrow < N);

    const int tm = (tid >> 4) * 8;       // 0..120, row offset of this thread's 8x8
    const int tn = (tid & 15) * 8;       // 0..120, col offset

    float acc[8][8];
    #pragma unroll
    for (int i = 0; i < 8; ++i)
        #pragma unroll
        for (int j = 0; j < 8; ++j) acc[i][j] = 0.f;

    float4 a_reg = *(const float4*)Aptr;
    float4 w_reg = wvalid ? *(const float4*)Wptr : float4{0.f,0.f,0.f,0.f};

    for (int k0 = 0; k0 < K; k0 += 8) {
        As[lk+0][lr] = a_reg.x; As[lk+1][lr] = a_reg.y;
        As[lk+2][lr] = a_reg.z; As[lk+3][lr] = a_reg.w;
        Ws[lk+0][lr] = w_reg.x; Ws[lk+1][lr] = w_reg.y;
        Ws[lk+2][lr] = w_reg.z; Ws[lk+3][lr] = w_reg.w;
        __syncthreads();

        if (k0 + 8 < K) {   // prefetch next K-slab into registers
            a_reg = *(const float4*)(Aptr + k0 + 8);
            w_reg = wvalid ? *(const float4*)(Wptr + k0 + 8) : float4{0.f,0.f,0.f,0.f};
        }

        #pragma unroll
        for (int kk = 0; kk < 8; ++kk) {
            float4 a0 = *(const float4*)&As[kk][tm];
            float4 a1 = *(const float4*)&As[kk][tm + 4];
            float4 b0 = *(const float4*)&Ws[kk][tn];
            float4 b1 = *(const float4*)&Ws[kk][tn + 4];
            float av[8] = {a0.x,a0.y,a0.z,a0.w,a1.x,a1.y,a1.z,a1.w};
            float bv[8] = {b0.x,b0.y,b0.z,b0.w,b1.x,b1.y,b1.z,b1.w};
            #pragma unroll
            for (int i = 0; i < 8; ++i)
                #pragma unroll
                for (int j = 0; j < 8; ++j)
                    acc[i][j] = fmaf(av[i], bv[j], acc[i][j]);
        }
        __syncthreads();
    }

    #pragma unroll
    for (int i = 0; i < 8; ++i) {
        const int r = row0 + tm + i;
        #pragma unroll
        for (int j = 0; j < 8; ++j) {
            const int c = col0 + tn + j;
            if (c < N) {
                float v = acc[i][j];
                if (bias) v += bias[c];
                if (GELU) v = gelu_exact(v);
                C[(size_t)r * N + c] = v * scale;
            }
        }
    }
}

// ---------------------------------------------------------------- LayerNorm (+ variants)
// Y[row] = LN(X[row] (+R[row])) * w + b  [then GELU] [then += sincos PE]
// width = VPT*256, one block (256 threads) per row.
template<int VPT, bool GELU, bool ADD_PE, bool RES>
__global__ __launch_bounds__(256)
void ln_kernel(const float* __restrict__ X, const float* __restrict__ R,
               const float* __restrict__ w, const float* __restrict__ b,
               float* __restrict__ Y, int T)
{
    const int W = VPT * 256;
    __shared__ float sbuf[4];
    const int row = blockIdx.x;
    const float* xr = X + (size_t)row * W;

    float v[VPT];
    if (VPT == 4) {
        float4 t4 = *(const float4*)(xr + threadIdx.x * 4);
        v[0] = t4.x; v[1] = t4.y; v[2] = t4.z; v[3] = t4.w;
        if (RES) {
            float4 r4 = *(const float4*)(R + (size_t)row * W + threadIdx.x * 4);
            v[0] += r4.x; v[1] += r4.y; v[2] += r4.z; v[3] += r4.w;
        }
    } else {
        v[0] = xr[threadIdx.x];
        if (RES) v[0] += R[(size_t)row * W + threadIdx.x];
    }

    float s = 0.f;
    #pragma unroll
    for (int j = 0; j < VPT; ++j) s += v[j];
    const float mean = block_sum_256(s, sbuf) / (float)W;

    float q = 0.f;
    #pragma unroll
    for (int j = 0; j < VPT; ++j) { float d = v[j] - mean; q += d * d; }
    const float var  = block_sum_256(q, sbuf) / (float)W;
    const float rstd = rsqrtf(var + 1e-6f);

    #pragma unroll
    for (int j = 0; j < VPT; ++j) {
        const int c = (VPT == 4) ? (threadIdx.x * 4 + j) : (int)threadIdx.x;
        float y = (v[j] - mean) * rstd * w[c] + b[c];
        if (GELU) y = gelu_exact(y);
        if (ADD_PE) {
            const int t = row % T;
            const float cc = (float)(c & ~1);
            const float div = expf(cc * (-9.210340371976184f / 256.0f)); // -ln(10000)/dim
            const float ang = (float)t * div;
            y += (c & 1) ? cosf(ang) : sinf(ang);
        }
        Y[(size_t)row * W + c] = y;
    }
}

// ---------------------------------------------------------------- causal attention, T=20, hd=64
// one wave (64 threads) per (batch, head). qkv: [B*T, 768], out: [B*T, 256]
__global__ __launch_bounds__(64)
void attn_kernel(const float* __restrict__ qkv, float* __restrict__ out,
                 int B, int T, int H)
{
    __shared__ float qs[20][65];
    __shared__ float ks[20][65];
    __shared__ float vs[20][65];
    __shared__ float probs[64];

    const int blk = blockIdx.x;
    const int b = blk / H;
    const int h = blk % H;
    const int tid = threadIdx.x;

    for (int t = 0; t < T; ++t) {
        const float* base = qkv + (size_t)(b * T + t) * 768 + h * 64 + tid;
        qs[t][tid] = base[0];
        ks[t][tid] = base[256];
        vs[t][tid] = base[512];
    }
    __syncthreads();

    for (int t = 0; t < T; ++t) {
        float sc = -INFINITY;
        if (tid <= t) {
            float s = 0.f;
            #pragma unroll
            for (int d = 0; d < 64; ++d) s = fmaf(qs[t][d], ks[tid][d], s);
            sc = s * 0.125f;  // 1/sqrt(64)
        }
        float m = sc;
        #pragma unroll
        for (int off = 32; off; off >>= 1) m = fmaxf(m, __shfl_xor(m, off, 64));
        float p = (tid <= t) ? expf(sc - m) : 0.f;
        float sum = p;
        #pragma unroll
        for (int off = 32; off; off >>= 1) sum += __shfl_xor(sum, off, 64);
        p /= sum;
        probs[tid] = p;
        __syncthreads();

        float o = 0.f;
        for (int s = 0; s <= t; ++s) o = fmaf(probs[s], vs[s][tid], o);
        out[(size_t)(b * T + t) * 256 + h * 64 + tid] = o;
        __syncthreads();
    }
}

// ---------------------------------------------------------------- row-wise L2 normalize, width 256
__global__ __launch_bounds__(256)
void l2norm_kernel(const float* __restrict__ X, float* __restrict__ Y)
{
    __shared__ float sbuf[4];
    const int row = blockIdx.x;
    const float v = X[(size_t)row * 256 + threadIdx.x];
    float s = v * v;
    #pragma unroll
    for (int off = 32; off; off >>= 1) s += __shfl_down(s, off, 64);
    const int lane = threadIdx.x & 63, wid = threadIdx.x >> 6;
    if (lane == 0) sbuf[wid] = s;
    __syncthreads();
    float n = sqrtf(sbuf[0] + sbuf[1] + sbuf[2] + sbuf[3]);
    n = fmaxf(n, 1e-12f);
    Y[(size_t)row * 256 + threadIdx.x] = v / n;
}

// ---------------------------------------------------------------- driver
extern "C" void kernel_launch(void* const* d_in, const int* in_sizes, int n_in,
                              void* d_out, int out_size, void* d_ws, size_t ws_size,
                              hipStream_t stream)
{
    const float* x         = (const float*)d_in[0];
    const float* p1_w      = (const float*)d_in[1];
    const float* p1_b      = (const float*)d_in[2];
    const float* pln1_w    = (const float*)d_in[3];
    const float* pln1_b    = (const float*)d_in[4];
    const float* p2_w      = (const float*)d_in[5];
    const float* pln2_w    = (const float*)d_in[6];
    const float* pln2_b    = (const float*)d_in[7];
    const float* in_proj_w = (const float*)d_in[8];
    const float* in_proj_b = (const float*)d_in[9];
    const float* out_proj_w= (const float*)d_in[10];
    const float* out_proj_b= (const float*)d_in[11];
    const float* ln1_w     = (const float*)d_in[12];
    const float* ln1_b     = (const float*)d_in[13];
    const float* lin1_w    = (const float*)d_in[14];
    const float* lin1_b    = (const float*)d_in[15];
    const float* lin2_w    = (const float*)d_in[16];
    const float* lin2_b    = (const float*)d_in[17];
    const float* ln2_w     = (const float*)d_in[18];
    const float* ln2_b     = (const float*)d_in[19];
    const float* head_w    = (const float*)d_in[20];

    const int B = 2048, T = 20, D = 2048, E = 256, HID = 1024, CLS = 1000, L = 2, H = 4;
    const int M = B * T;   // 40960

    float* ws    = (float*)d_ws;
    float* h1    = ws;                                  // M*HID   (proj hidden / FF hidden)
    float* h     = h1 + (size_t)M * HID;                // M*E     (token state)
    float* attnb = h + (size_t)M * E;                   // M*E     (attn heads out / ff2 out)
    float* wn    = attnb + (size_t)M * E;               // CLS*E   (normalized head_w)

    float* out   = (float*)d_out;
    float* qkv   = out;                                 // M*768 scratch inside d_out
    float* attnp = out;                                 // M*E scratch (qkv dead by then)

    // ---- projector ----
    // h1 = x @ p1_w^T + p1_b
    sgemm_kernel<false><<<dim3(HID/128, M/128), 256, 0, stream>>>(x, p1_w, p1_b, h1, M, HID, D, 1.f);
    // h1 = gelu(LN(h1))
    ln_kernel<4, true, false, false><<<M, 256, 0, stream>>>(h1, nullptr, pln1_w, pln1_b, h1, T);
    // h = h1 @ p2_w^T
    sgemm_kernel<false><<<dim3(E/128, M/128), 256, 0, stream>>>(h1, p2_w, nullptr, h, M, E, HID, 1.f);
    // h = LN(h) + PE
    ln_kernel<1, false, true, false><<<M, 256, 0, stream>>>(h, nullptr, pln2_w, pln2_b, h, T);

    // ---- transformer layers (post-norm) ----
    for (int l = 0; l < L; ++l) {
        sgemm_kernel<false><<<dim3(768/128, M/128), 256, 0, stream>>>(
            h, in_proj_w + (size_t)l*768*E, in_proj_b + (size_t)l*768, qkv, M, 768, E, 1.f);
        attn_kernel<<<B*H, 64, 0, stream>>>(qkv, attnb, B, T, H);
        sgemm_kernel<false><<<dim3(E/128, M/128), 256, 0, stream>>>(
            attnb, out_proj_w + (size_t)l*E*E, out_proj_b + (size_t)l*E, attnp, M, E, E, 1.f);
        ln_kernel<1, false, false, true><<<M, 256, 0, stream>>>(
            h, attnp, ln1_w + (size_t)l*E, ln1_b + (size_t)l*E, h, T);
        sgemm_kernel<true><<<dim3(HID/128, M/128), 256, 0, stream>>>(
            h, lin1_w + (size_t)l*HID*E, lin1_b + (size_t)l*HID, h1, M, HID, E, 1.f);
        sgemm_kernel<false><<<dim3(E/128, M/128), 256, 0, stream>>>(
            h1, lin2_w + (size_t)l*E*HID, lin2_b + (size_t)l*E, attnb, M, E, HID, 1.f);
        ln_kernel<1, false, false, true><<<M, 256, 0, stream>>>(
            h, attnb, ln2_w + (size_t)l*E, ln2_b + (size_t)l*E, h, T);
    }

    // ---- head ----
    l2norm_kernel<<<M, 256, 0, stream>>>(h, h);          // flat = normalize(h)
    l2norm_kernel<<<CLS, 256, 0, stream>>>(head_w, wn);  // wn = normalize(head_w)
    // out = flat @ wn^T / tau
    sgemm_kernel<false><<<dim3(CDIV(CLS,128), M/128), 256, 0, stream>>>(
        h, wn, nullptr, out, M, CLS, E, 10.f);
}

// Round 2
// 1545.407 us; speedup vs baseline: 3.3937x; 3.3937x over previous
//
#include <hip/hip_runtime.h>
#include <math.h>

#define CDIV(a,b) (((a)+(b)-1)/(b))

typedef unsigned short bfu;                                   // bf16 bits
typedef short   s16x8 __attribute__((ext_vector_type(8)));    // MFMA A/B frag (8 bf16)
typedef float   f32x4 __attribute__((ext_vector_type(4)));    // MFMA C/D frag

// ---------------------------------------------------------------- helpers
static __device__ __forceinline__ float gelu_exact(float x) {
    return 0.5f * x * (1.0f + erff(x * 0.7071067811865475f));
}
static __device__ __forceinline__ bfu f2bf(float x) {         // RNE f32->bf16
    unsigned int u = __float_as_uint(x);
    unsigned int r = u + 0x7fffu + ((u >> 16) & 1u);
    return (bfu)(r >> 16);
}
static __device__ __forceinline__ float bf2f(bfu b) {
    return __uint_as_float(((unsigned int)b) << 16);
}

static __device__ __forceinline__ float block_sum_256(float v, float* sbuf) {
    #pragma unroll
    for (int off = 32; off; off >>= 1) v += __shfl_down(v, off, 64);
    const int lane = threadIdx.x & 63;
    const int wid  = threadIdx.x >> 6;
    __syncthreads();
    if (lane == 0) sbuf[wid] = v;
    __syncthreads();
    return sbuf[0] + sbuf[1] + sbuf[2] + sbuf[3];
}

// ---------------------------------------------------------------- fp32 -> bf16 convert
__global__ __launch_bounds__(256)
void cvt_kernel(const float* __restrict__ in, bfu* __restrict__ out, int n4)
{
    int i = blockIdx.x * 256 + threadIdx.x;
    const int stride = gridDim.x * 256;
    for (; i < n4; i += stride) {
        float4 f = ((const float4*)in)[i];
        ushort4 o;
        o.x = f2bf(f.x); o.y = f2bf(f.y); o.z = f2bf(f.z); o.w = f2bf(f.w);
        ((ushort4*)out)[i] = o;
    }
}

// ---------------------------------------------------------------- MFMA GEMM
// C[M,N] = scale * epi(A[M,K] @ W[N,K]^T + bias)
// 128x128 tile, BK=32, 256 threads (4 waves, each 64x64 via 4x4 frags of 16x16x32).
// A is fp32 (converted in staging) or bf16. W is bf16. M%128==0, K%32==0, N checked.
// LDS row stride 40 bf16 (80B) -> frag ds_read_b128 lands on 8 distinct banks (2-way, free).
template<bool A_FP32, bool GELU_EP, bool OUT_BF16>
__global__ __launch_bounds__(256)
void mfma_gemm(const void* __restrict__ Av, const bfu* __restrict__ W,
               const float* __restrict__ bias, void* __restrict__ Cv,
               int M, int N, int K, float scale)
{
    __shared__ bfu As[128 * 40];
    __shared__ bfu Ws[128 * 40];

    const int tid  = threadIdx.x;
    const int row0 = blockIdx.y * 128;
    const int col0 = blockIdx.x * 128;

    // staging: thread t owns row sr, k-halfsegment sk (16 bf16 elems)
    const int sr = tid >> 1;
    const int sk = (tid & 1) * 16;

    const int lane = tid & 63;
    const int wave = tid >> 6;
    const int wm = (wave >> 1) * 64;
    const int wn = (wave & 1) * 64;
    const int fr = lane & 15;           // frag row/col
    const int fk = (lane >> 4) * 8;     // frag k offset

    const float* Af = (const float*)Av;
    const bfu*   Ab = (const bfu*)Av;

    const int  wrow = col0 + sr;
    const bool wok  = wrow < N;
    const bfu* Wp   = W + (size_t)wrow * K + sk;

    s16x8 areg0, areg1, wreg0, wreg1;
    s16x8 zed;
    #pragma unroll
    for (int i = 0; i < 8; ++i) zed[i] = 0;

    auto loadA = [&](int k0) {
        if (A_FP32) {
            const float* p = Af + (size_t)(row0 + sr) * K + k0 + sk;
            float4 f0 = *(const float4*)(p + 0);
            float4 f1 = *(const float4*)(p + 4);
            float4 f2 = *(const float4*)(p + 8);
            float4 f3 = *(const float4*)(p + 12);
            s16x8 r0, r1;
            r0[0]=(short)f2bf(f0.x); r0[1]=(short)f2bf(f0.y); r0[2]=(short)f2bf(f0.z); r0[3]=(short)f2bf(f0.w);
            r0[4]=(short)f2bf(f1.x); r0[5]=(short)f2bf(f1.y); r0[6]=(short)f2bf(f1.z); r0[7]=(short)f2bf(f1.w);
            r1[0]=(short)f2bf(f2.x); r1[1]=(short)f2bf(f2.y); r1[2]=(short)f2bf(f2.z); r1[3]=(short)f2bf(f2.w);
            r1[4]=(short)f2bf(f3.x); r1[5]=(short)f2bf(f3.y); r1[6]=(short)f2bf(f3.z); r1[7]=(short)f2bf(f3.w);
            areg0 = r0; areg1 = r1;
        } else {
            const bfu* p = Ab + (size_t)(row0 + sr) * K + k0 + sk;
            areg0 = *(const s16x8*)(p);
            areg1 = *(const s16x8*)(p + 8);
        }
    };
    auto loadW = [&](int k0) {
        if (wok) {
            wreg0 = *(const s16x8*)(Wp + k0);
            wreg1 = *(const s16x8*)(Wp + k0 + 8);
        } else { wreg0 = zed; wreg1 = zed; }
    };

    f32x4 acc[4][4];
    #pragma unroll
    for (int i = 0; i < 4; ++i)
        #pragma unroll
        for (int j = 0; j < 4; ++j) acc[i][j] = (f32x4)0.f;

    loadA(0); loadW(0);

    for (int k0 = 0; k0 < K; k0 += 32) {
        *(s16x8*)&As[sr * 40 + sk]     = areg0;
        *(s16x8*)&As[sr * 40 + sk + 8] = areg1;
        *(s16x8*)&Ws[sr * 40 + sk]     = wreg0;
        *(s16x8*)&Ws[sr * 40 + sk + 8] = wreg1;
        __syncthreads();

        if (k0 + 32 < K) { loadA(k0 + 32); loadW(k0 + 32); }

        s16x8 af[4], wf[4];
        #pragma unroll
        for (int i = 0; i < 4; ++i) af[i] = *(const s16x8*)&As[(wm + 16*i + fr) * 40 + fk];
        #pragma unroll
        for (int j = 0; j < 4; ++j) wf[j] = *(const s16x8*)&Ws[(wn + 16*j + fr) * 40 + fk];

        #pragma unroll
        for (int i = 0; i < 4; ++i)
            #pragma unroll
            for (int j = 0; j < 4; ++j)
                acc[i][j] = __builtin_amdgcn_mfma_f32_16x16x32_bf16(af[i], wf[j], acc[i][j], 0, 0, 0);
        __syncthreads();
    }

    // epilogue: D[4*(lane>>4)+rr][lane&15] per frag
    #pragma unroll
    for (int i = 0; i < 4; ++i) {
        const int r = row0 + wm + 16 * i + (lane >> 4) * 4;
        #pragma unroll
        for (int j = 0; j < 4; ++j) {
            const int c = col0 + wn + 16 * j + fr;
            if (c < N) {
                const float bsum = bias ? bias[c] : 0.f;
                #pragma unroll
                for (int rr = 0; rr < 4; ++rr) {
                    float v = acc[i][j][rr] + bsum;
                    if (GELU_EP) v = gelu_exact(v);
                    v *= scale;
                    if (OUT_BF16) ((bfu*)Cv)[(size_t)(r + rr) * N + c] = f2bf(v);
                    else          ((float*)Cv)[(size_t)(r + rr) * N + c] = v;
                }
            }
        }
    }
}

// ---------------------------------------------------------------- LayerNorm variants
// width = VPT*256. Optional: input bf16, +residual(fp32), GELU, +sincos PE.
// Writes fp32 (Yf) and/or bf16 (Yb); pass nullptr to skip.
template<int VPT, bool GELU_EP, bool ADD_PE, bool RES, bool IN_BF16>
__global__ __launch_bounds__(256)
void ln_kernel(const void* __restrict__ Xv, const float* __restrict__ R,
               const float* __restrict__ w, const float* __restrict__ b,
               float* __restrict__ Yf, bfu* __restrict__ Yb, int T)
{
    const int W = VPT * 256;
    __shared__ float sbuf[4];
    const int row = blockIdx.x;

    float v[VPT];
    if (IN_BF16) {
        const bfu* xr = (const bfu*)Xv + (size_t)row * W;
        if (VPT == 4) {
            ushort4 t4 = *(const ushort4*)(xr + threadIdx.x * 4);
            v[0] = bf2f(t4.x); v[1] = bf2f(t4.y); v[2] = bf2f(t4.z); v[3] = bf2f(t4.w);
        } else {
            v[0] = bf2f(xr[threadIdx.x]);
        }
    } else {
        const float* xr = (const float*)Xv + (size_t)row * W;
        if (VPT == 4) {
            float4 t4 = *(const float4*)(xr + threadIdx.x * 4);
            v[0] = t4.x; v[1] = t4.y; v[2] = t4.z; v[3] = t4.w;
        } else {
            v[0] = xr[threadIdx.x];
        }
    }
    if (RES) {
        #pragma unroll
        for (int j = 0; j < VPT; ++j)
            v[j] += R[(size_t)row * W + ((VPT == 4) ? threadIdx.x * 4 + j : (int)threadIdx.x)];
    }

    float s = 0.f;
    #pragma unroll
    for (int j = 0; j < VPT; ++j) s += v[j];
    const float mean = block_sum_256(s, sbuf) / (float)W;

    float q = 0.f;
    #pragma unroll
    for (int j = 0; j < VPT; ++j) { float d = v[j] - mean; q += d * d; }
    const float var  = block_sum_256(q, sbuf) / (float)W;
    const float rstd = rsqrtf(var + 1e-6f);

    #pragma unroll
    for (int j = 0; j < VPT; ++j) {
        const int c = (VPT == 4) ? (threadIdx.x * 4 + j) : (int)threadIdx.x;
        float y = (v[j] - mean) * rstd * w[c] + b[c];
        if (GELU_EP) y = gelu_exact(y);
        if (ADD_PE) {
            const int t = row % T;
            const float cc  = (float)(c & ~1);
            const float div = expf(cc * (-9.210340371976184f / 256.0f));
            const float ang = (float)t * div;
            y += (c & 1) ? cosf(ang) : sinf(ang);
        }
        if (Yf) Yf[(size_t)row * W + c] = y;
        if (Yb) Yb[(size_t)row * W + c] = f2bf(y);
    }
}

// ---------------------------------------------------------------- causal attention, T=20, hd=64
// one wave per (batch, head). qkv fp32 [B*T,768] -> out bf16 [B*T,256]
__global__ __launch_bounds__(64)
void attn_kernel(const float* __restrict__ qkv, bfu* __restrict__ out,
                 int B, int T, int H)
{
    __shared__ float qs[20][65];
    __shared__ float ks[20][65];
    __shared__ float vs[20][65];
    __shared__ float probs[64];

    const int blk = blockIdx.x;
    const int b = blk / H;
    const int h = blk % H;
    const int tid = threadIdx.x;

    for (int t = 0; t < T; ++t) {
        const float* base = qkv + (size_t)(b * T + t) * 768 + h * 64 + tid;
        qs[t][tid] = base[0];
        ks[t][tid] = base[256];
        vs[t][tid] = base[512];
    }
    __syncthreads();

    for (int t = 0; t < T; ++t) {
        float sc = -INFINITY;
        if (tid <= t) {
            float s = 0.f;
            #pragma unroll
            for (int d = 0; d < 64; ++d) s = fmaf(qs[t][d], ks[tid][d], s);
            sc = s * 0.125f;
        }
        float m = sc;
        #pragma unroll
        for (int off = 32; off; off >>= 1) m = fmaxf(m, __shfl_xor(m, off, 64));
        float p = (tid <= t) ? expf(sc - m) : 0.f;
        float sum = p;
        #pragma unroll
        for (int off = 32; off; off >>= 1) sum += __shfl_xor(sum, off, 64);
        p /= sum;
        probs[tid] = p;
        __syncthreads();

        float o = 0.f;
        for (int s = 0; s <= t; ++s) o = fmaf(probs[s], vs[s][tid], o);
        out[(size_t)(b * T + t) * 256 + h * 64 + tid] = f2bf(o);
        __syncthreads();
    }
}

// ---------------------------------------------------------------- row L2 normalize (width 256) -> bf16
__global__ __launch_bounds__(256)
void l2norm_kernel(const float* __restrict__ X, bfu* __restrict__ Y)
{
    __shared__ float sbuf[4];
    const int row = blockIdx.x;
    const float v = X[(size_t)row * 256 + threadIdx.x];
    float s = v * v;
    #pragma unroll
    for (int off = 32; off; off >>= 1) s += __shfl_down(s, off, 64);
    const int lane = threadIdx.x & 63, wid = threadIdx.x >> 6;
    if (lane == 0) sbuf[wid] = s;
    __syncthreads();
    float n = sqrtf(sbuf[0] + sbuf[1] + sbuf[2] + sbuf[3]);
    n = fmaxf(n, 1e-12f);
    Y[(size_t)row * 256 + threadIdx.x] = f2bf(v / n);
}

// ---------------------------------------------------------------- driver
extern "C" void kernel_launch(void* const* d_in, const int* in_sizes, int n_in,
                              void* d_out, int out_size, void* d_ws, size_t ws_size,
                              hipStream_t stream)
{
    const float* x         = (const float*)d_in[0];
    const float* p1_w      = (const float*)d_in[1];
    const float* p1_b      = (const float*)d_in[2];
    const float* pln1_w    = (const float*)d_in[3];
    const float* pln1_b    = (const float*)d_in[4];
    const float* p2_w      = (const float*)d_in[5];
    const float* pln2_w    = (const float*)d_in[6];
    const float* pln2_b    = (const float*)d_in[7];
    const float* in_proj_w = (const float*)d_in[8];
    const float* in_proj_b = (const float*)d_in[9];
    const float* out_proj_w= (const float*)d_in[10];
    const float* out_proj_b= (const float*)d_in[11];
    const float* ln1_w     = (const float*)d_in[12];
    const float* ln1_b     = (const float*)d_in[13];
    const float* lin1_w    = (const float*)d_in[14];
    const float* lin1_b    = (const float*)d_in[15];
    const float* lin2_w    = (const float*)d_in[16];
    const float* lin2_b    = (const float*)d_in[17];
    const float* ln2_w     = (const float*)d_in[18];
    const float* ln2_b     = (const float*)d_in[19];
    const float* head_w    = (const float*)d_in[20];

    const int B = 2048, T = 20, E = 256, HID = 1024, CLS = 1000, L = 2, H = 4;
    const int M = B * T;   // 40960
    const int D = 2048;

    // ---- workspace carve-up (~218 MB) ----
    char* p = (char*)d_ws;
    float* h      = (float*)p;  p += (size_t)M * E * 4;        // token state (fp32 residual)
    float* ffout  = (float*)p;  p += (size_t)M * E * 4;        // ff2 output fp32
    bfu*   hb     = (bfu*)p;    p += (size_t)M * E * 2;        // bf16 copy of h (GEMM A)
    bfu*   h1b    = (bfu*)p;    p += (size_t)M * HID * 2;      // proj hidden / FF hidden bf16
    bfu*   abf    = (bfu*)p;    p += (size_t)M * E * 2;        // attention out bf16
    bfu*   p1wb   = (bfu*)p;    p += (size_t)HID * D * 2;
    bfu*   p2wb   = (bfu*)p;    p += (size_t)E * HID * 2;
    bfu*   qkvwb  = (bfu*)p;    p += (size_t)L * 3 * E * E * 2;
    bfu*   outwb  = (bfu*)p;    p += (size_t)L * E * E * 2;
    bfu*   l1wb   = (bfu*)p;    p += (size_t)L * 4 * E * E * 2;
    bfu*   l2wb   = (bfu*)p;    p += (size_t)L * E * 4 * E * 2;
    bfu*   wnb    = (bfu*)p;    p += (size_t)CLS * E * 2;

    float* out   = (float*)d_out;
    float* qkv   = out;                 // [M,768] fp32 scratch inside d_out
    float* attnp = out;                 // [M,256] fp32 scratch (qkv dead by then)

    // ---- weights -> bf16 ----
    auto cvt = [&](const float* src, bfu* dst, size_t n) {
        int n4 = (int)(n / 4);
        int blocks = CDIV(n4, 256); if (blocks > 2048) blocks = 2048;
        cvt_kernel<<<blocks, 256, 0, stream>>>(src, dst, n4);
    };
    cvt(p1_w,       p1wb,  (size_t)HID * D);
    cvt(p2_w,       p2wb,  (size_t)E * HID);
    cvt(in_proj_w,  qkvwb, (size_t)L * 3 * E * E);
    cvt(out_proj_w, outwb, (size_t)L * E * E);
    cvt(lin1_w,     l1wb,  (size_t)L * 4 * E * E);
    cvt(lin2_w,     l2wb,  (size_t)L * E * 4 * E);

    // ---- projector ----
    // h1b = bf16( x @ p1_w^T + p1_b )
    mfma_gemm<true, false, true><<<dim3(HID/128, M/128), 256, 0, stream>>>(
        x, p1wb, p1_b, h1b, M, HID, D, 1.f);
    // h1b = bf16( gelu(LN(h1b)) )
    ln_kernel<4, true, false, false, true><<<M, 256, 0, stream>>>(
        h1b, nullptr, pln1_w, pln1_b, nullptr, h1b, T);
    // h = h1b @ p2_w^T   (fp32 out)
    mfma_gemm<false, false, false><<<dim3(E/128, M/128), 256, 0, stream>>>(
        h1b, p2wb, nullptr, h, M, E, HID, 1.f);
    // h = LN(h) + PE ; hb = bf16(h)
    ln_kernel<1, false, true, false, false><<<M, 256, 0, stream>>>(
        h, nullptr, pln2_w, pln2_b, h, hb, T);

    // ---- transformer layers (post-norm) ----
    for (int l = 0; l < L; ++l) {
        mfma_gemm<false, false, false><<<dim3(768/128, M/128), 256, 0, stream>>>(
            hb, qkvwb + (size_t)l * 3*E*E, in_proj_b + (size_t)l * 3*E, qkv, M, 3*E, E, 1.f);
        attn_kernel<<<B * H, 64, 0, stream>>>(qkv, abf, B, T, H);
        mfma_gemm<false, false, false><<<dim3(E/128, M/128), 256, 0, stream>>>(
            abf, outwb + (size_t)l * E*E, out_proj_b + (size_t)l * E, attnp, M, E, E, 1.f);
        ln_kernel<1, false, false, true, false><<<M, 256, 0, stream>>>(
            h, attnp, ln1_w + (size_t)l * E, ln1_b + (size_t)l * E, h, hb, T);
        mfma_gemm<false, true, true><<<dim3(HID/128, M/128), 256, 0, stream>>>(
            hb, l1wb + (size_t)l * 4*E*E, lin1_b + (size_t)l * 4*E, h1b, M, HID, E, 1.f);
        mfma_gemm<false, false, false><<<dim3(E/128, M/128), 256, 0, stream>>>(
            h1b, l2wb + (size_t)l * E*4*E, lin2_b + (size_t)l * E, ffout, M, E, HID, 1.f);
        ln_kernel<1, false, false, true, false><<<M, 256, 0, stream>>>(
            h, ffout, ln2_w + (size_t)l * E, ln2_b + (size_t)l * E, h, hb, T);
    }

    // ---- head ----
    l2norm_kernel<<<M, 256, 0, stream>>>(h, hb);           // flat = bf16(normalize(h))
    l2norm_kernel<<<CLS, 256, 0, stream>>>(head_w, wnb);   // wn  = bf16(normalize(head_w))
    mfma_gemm<false, false, false><<<dim3(CDIV(CLS,128), M/128), 256, 0, stream>>>(
        hb, wnb, nullptr, out, M, CLS, E, 10.f);
}

// Round 3
// 1437.077 us; speedup vs baseline: 3.6495x; 1.0754x over previous
//
#include <hip/hip_runtime.h>
#include <math.h>

#define CDIV(a,b) (((a)+(b)-1)/(b))

typedef unsigned short bfu;                                   // bf16 bits
typedef short   s16x8 __attribute__((ext_vector_type(8)));    // MFMA A/B frag (8 bf16)
typedef float   f32x4 __attribute__((ext_vector_type(4)));    // MFMA C/D frag

// async global->LDS, 16B per lane. LDS dst must be wave-uniform; HW writes base+lane*16.
#define GLOAD16(gp, lp) __builtin_amdgcn_global_load_lds( \
    (const __attribute__((address_space(1))) void*)(gp),  \
    (__attribute__((address_space(3))) void*)(lp), 16, 0, 0)

// ---------------------------------------------------------------- helpers
static __device__ __forceinline__ float gelu_exact(float x) {
    return 0.5f * x * (1.0f + erff(x * 0.7071067811865475f));
}
static __device__ __forceinline__ bfu f2bf(float x) {         // RNE f32->bf16
    unsigned int u = __float_as_uint(x);
    unsigned int r = u + 0x7fffu + ((u >> 16) & 1u);
    return (bfu)(r >> 16);
}
static __device__ __forceinline__ float bf2f(bfu b) {
    return __uint_as_float(((unsigned int)b) << 16);
}

static __device__ __forceinline__ float block_sum_256(float v, float* sbuf) {
    #pragma unroll
    for (int off = 32; off; off >>= 1) v += __shfl_down(v, off, 64);
    const int lane = threadIdx.x & 63;
    const int wid  = threadIdx.x >> 6;
    __syncthreads();
    if (lane == 0) sbuf[wid] = v;
    __syncthreads();
    return sbuf[0] + sbuf[1] + sbuf[2] + sbuf[3];
}

// ---------------------------------------------------------------- fused weight convert
// all 6 bf16 weight buffers are laid out contiguously at dst; region sizes in float4 units.
__global__ __launch_bounds__(256)
void cvt6_kernel(const float* __restrict__ s0, const float* __restrict__ s1,
                 const float* __restrict__ s2, const float* __restrict__ s3,
                 const float* __restrict__ s4, const float* __restrict__ s5,
                 bfu* __restrict__ dst)
{
    const int c0 = 524288;           // p1_w  1024*2048/4
    const int c1 = c0 + 65536;       // p2_w  256*1024/4
    const int c2 = c1 + 98304;       // in_proj 2*768*256/4
    const int c3 = c2 + 32768;       // out_proj 2*256*256/4
    const int c4 = c3 + 131072;      // lin1 2*1024*256/4
    const int c5 = c4 + 131072;      // lin2 2*256*1024/4
    int i = blockIdx.x * 256 + threadIdx.x;
    const int stride = gridDim.x * 256;
    for (; i < c5; i += stride) {
        const float* s; int base;
        if      (i < c0) { s = s0; base = 0;  }
        else if (i < c1) { s = s1; base = c0; }
        else if (i < c2) { s = s2; base = c1; }
        else if (i < c3) { s = s3; base = c2; }
        else if (i < c4) { s = s4; base = c3; }
        else             { s = s5; base = c4; }
        float4 f = ((const float4*)s)[i - base];
        ushort4 o;
        o.x = f2bf(f.x); o.y = f2bf(f.y); o.z = f2bf(f.z); o.w = f2bf(f.w);
        ((ushort4*)dst)[i] = o;
    }
}

// ---------------------------------------------------------------- MFMA GEMM (m97 structure)
// C[M,N] = scale * epi(A[M,K] @ W[N,K]^T + bias)
// 128x128 tile, BK=32, 256 threads (4 waves, 4x4 frags of 16x16x32 each).
// Staging: global_load_lds dwordx4 into linear LDS [128][32] bf16 (64B rows).
// A_FP32: A reg-staged fp32->bf16 (proj1 only). XCD-chunk swizzle on 1-D grid.
// M%128==0, K%32==0; N tiles may read pad W rows (caller guarantees mapped memory;
// garbage pad rows only pollute never-stored output columns).
template<bool A_FP32, bool GELU_EP, bool OUT_BF16>
__global__ __launch_bounds__(256)
void mfma_gemm(const void* __restrict__ Av, const bfu* __restrict__ W,
               const float* __restrict__ bias, void* __restrict__ Cv,
               int M, int N, int K, float scale, int ntx)
{
    __shared__ bfu As[128 * 32];
    __shared__ bfu Ws[128 * 32];

    const int tid = threadIdx.x;
    const int nwg = gridDim.x;
    // XCD swizzle: dispatch round-robins blockIdx%8 across XCDs; give each XCD a
    // contiguous chunk of logical ids so same-A-panel tiles share one L2.
    const int lid = (nwg & 7) ? (int)blockIdx.x
                              : ((int)blockIdx.x & 7) * (nwg >> 3) + ((int)blockIdx.x >> 3);
    const int row0 = (lid / ntx) * 128;
    const int col0 = (lid % ntx) * 128;

    const int lane = tid & 63;
    const int wave = tid >> 6;
    const int wm = (wave >> 1) * 64;
    const int wn = (wave & 1) * 64;
    const int fr = lane & 15;
    const int fk = (lane >> 4) * 8;

    const bfu*   Ab = (const bfu*)Av;
    const float* Af = (const float*)Av;

    // gload addressing: one wave-load covers 16 rows x 32 k (1KB). lane: row=l>>2, k=(l&3)*8.
    const int lrow = lane >> 2;
    const int lk   = (lane & 3) * 8;
    const bfu* wl0 = W + (size_t)(col0 + wave * 32 + lrow) * K + lk;
    const bfu* wl1 = wl0 + (size_t)16 * K;
    bfu* wd0 = &Ws[(wave * 2    ) * 512];
    bfu* wd1 = &Ws[(wave * 2 + 1) * 512];

    const bfu *al0 = nullptr, *al1 = nullptr;
    bfu *ad0 = nullptr, *ad1 = nullptr;
    const float* afp = nullptr;
    int sr = 0, skk = 0;
    if (!A_FP32) {
        al0 = Ab + (size_t)(row0 + wave * 32 + lrow) * K + lk;
        al1 = al0 + (size_t)16 * K;
        ad0 = &As[(wave * 2    ) * 512];
        ad1 = &As[(wave * 2 + 1) * 512];
    } else {
        sr  = tid >> 1;            // row 0..127
        skk = (tid & 1) * 16;      // k-half
        afp = Af + (size_t)(row0 + sr) * K + skk;
    }

    f32x4 acc[4][4];
    #pragma unroll
    for (int i = 0; i < 4; ++i)
        #pragma unroll
        for (int j = 0; j < 4; ++j) acc[i][j] = (f32x4)0.f;

    s16x8 areg0, areg1;
    auto loadAfp = [&](int k0) {
        const float* p = afp + k0;
        float4 f0 = *(const float4*)(p + 0);
        float4 f1 = *(const float4*)(p + 4);
        float4 f2 = *(const float4*)(p + 8);
        float4 f3 = *(const float4*)(p + 12);
        s16x8 r0, r1;
        r0[0]=(short)f2bf(f0.x); r0[1]=(short)f2bf(f0.y); r0[2]=(short)f2bf(f0.z); r0[3]=(short)f2bf(f0.w);
        r0[4]=(short)f2bf(f1.x); r0[5]=(short)f2bf(f1.y); r0[6]=(short)f2bf(f1.z); r0[7]=(short)f2bf(f1.w);
        r1[0]=(short)f2bf(f2.x); r1[1]=(short)f2bf(f2.y); r1[2]=(short)f2bf(f2.z); r1[3]=(short)f2bf(f2.w);
        r1[4]=(short)f2bf(f3.x); r1[5]=(short)f2bf(f3.y); r1[6]=(short)f2bf(f3.z); r1[7]=(short)f2bf(f3.w);
        areg0 = r0; areg1 = r1;
    };
    if (A_FP32) loadAfp(0);

    for (int k0 = 0; k0 < K; k0 += 32) {
        if (A_FP32) {
            *(s16x8*)&As[sr * 32 + skk]     = areg0;
            *(s16x8*)&As[sr * 32 + skk + 8] = areg1;
        } else {
            GLOAD16(al0 + k0, ad0);
            GLOAD16(al1 + k0, ad1);
        }
        GLOAD16(wl0 + k0, wd0);
        GLOAD16(wl1 + k0, wd1);
        __syncthreads();

        if (A_FP32 && k0 + 32 < K) loadAfp(k0 + 32);   // prefetch next A slab into regs

        s16x8 af[4], wf[4];
        #pragma unroll
        for (int i = 0; i < 4; ++i) af[i] = *(const s16x8*)&As[(wm + 16*i + fr) * 32 + fk];
        #pragma unroll
        for (int j = 0; j < 4; ++j) wf[j] = *(const s16x8*)&Ws[(wn + 16*j + fr) * 32 + fk];

        #pragma unroll
        for (int i = 0; i < 4; ++i)
            #pragma unroll
            for (int j = 0; j < 4; ++j)
                acc[i][j] = __builtin_amdgcn_mfma_f32_16x16x32_bf16(af[i], wf[j], acc[i][j], 0, 0, 0);
        __syncthreads();
    }

    // epilogue: D row = 4*(lane>>4)+rr, col = lane&15 within each 16x16 frag
    #pragma unroll
    for (int i = 0; i < 4; ++i) {
        const int r = row0 + wm + 16 * i + (lane >> 4) * 4;
        #pragma unroll
        for (int j = 0; j < 4; ++j) {
            const int c = col0 + wn + 16 * j + fr;
            if (c < N) {
                const float bsum = bias ? bias[c] : 0.f;
                #pragma unroll
                for (int rr = 0; rr < 4; ++rr) {
                    float v = acc[i][j][rr] + bsum;
                    if (GELU_EP) v = gelu_exact(v);
                    v *= scale;
                    if (OUT_BF16) ((bfu*)Cv)[(size_t)(r + rr) * N + c] = f2bf(v);
                    else          ((float*)Cv)[(size_t)(r + rr) * N + c] = v;
                }
            }
        }
    }
}

// ---------------------------------------------------------------- LayerNorm variants
template<int VPT, bool GELU_EP, bool ADD_PE, bool RES, bool IN_BF16>
__global__ __launch_bounds__(256)
void ln_kernel(const void* __restrict__ Xv, const float* __restrict__ R,
               const float* __restrict__ w, const float* __restrict__ b,
               float* __restrict__ Yf, bfu* __restrict__ Yb, int T)
{
    const int W = VPT * 256;
    __shared__ float sbuf[4];
    const int row = blockIdx.x;

    float v[VPT];
    if (IN_BF16) {
        const bfu* xr = (const bfu*)Xv + (size_t)row * W;
        if (VPT == 4) {
            ushort4 t4 = *(const ushort4*)(xr + threadIdx.x * 4);
            v[0] = bf2f(t4.x); v[1] = bf2f(t4.y); v[2] = bf2f(t4.z); v[3] = bf2f(t4.w);
        } else {
            v[0] = bf2f(xr[threadIdx.x]);
        }
    } else {
        const float* xr = (const float*)Xv + (size_t)row * W;
        if (VPT == 4) {
            float4 t4 = *(const float4*)(xr + threadIdx.x * 4);
            v[0] = t4.x; v[1] = t4.y; v[2] = t4.z; v[3] = t4.w;
        } else {
            v[0] = xr[threadIdx.x];
        }
    }
    if (RES) {
        #pragma unroll
        for (int j = 0; j < VPT; ++j)
            v[j] += R[(size_t)row * W + ((VPT == 4) ? threadIdx.x * 4 + j : (int)threadIdx.x)];
    }

    float s = 0.f;
    #pragma unroll
    for (int j = 0; j < VPT; ++j) s += v[j];
    const float mean = block_sum_256(s, sbuf) / (float)W;

    float q = 0.f;
    #pragma unroll
    for (int j = 0; j < VPT; ++j) { float d = v[j] - mean; q += d * d; }
    const float var  = block_sum_256(q, sbuf) / (float)W;
    const float rstd = rsqrtf(var + 1e-6f);

    #pragma unroll
    for (int j = 0; j < VPT; ++j) {
        const int c = (VPT == 4) ? (threadIdx.x * 4 + j) : (int)threadIdx.x;
        float y = (v[j] - mean) * rstd * w[c] + b[c];
        if (GELU_EP) y = gelu_exact(y);
        if (ADD_PE) {
            const int t = row % T;
            const float cc  = (float)(c & ~1);
            const float div = expf(cc * (-9.210340371976184f / 256.0f));
            const float ang = (float)t * div;
            y += (c & 1) ? cosf(ang) : sinf(ang);
        }
        if (Yf) Yf[(size_t)row * W + c] = y;
        if (Yb) Yb[(size_t)row * W + c] = f2bf(y);
    }
}

// ---------------------------------------------------------------- causal attention, T=20, hd=64
// one wave per (batch, head). qkv bf16 [B*T,768] -> out bf16 [B*T,256]
__global__ __launch_bounds__(64)
void attn_kernel(const bfu* __restrict__ qkv, bfu* __restrict__ out,
                 int B, int T, int H)
{
    __shared__ float qs[20][65];
    __shared__ float ks[20][65];
    __shared__ float vs[20][65];
    __shared__ float probs[64];

    const int blk = blockIdx.x;
    const int b = blk / H;
    const int h = blk % H;
    const int tid = threadIdx.x;

    for (int t = 0; t < T; ++t) {
        const bfu* base = qkv + (size_t)(b * T + t) * 768 + h * 64 + tid;
        qs[t][tid] = bf2f(base[0]);
        ks[t][tid] = bf2f(base[256]);
        vs[t][tid] = bf2f(base[512]);
    }
    __syncthreads();

    for (int t = 0; t < T; ++t) {
        float sc = -INFINITY;
        if (tid <= t) {
            float s = 0.f;
            #pragma unroll
            for (int d = 0; d < 64; ++d) s = fmaf(qs[t][d], ks[tid][d], s);
            sc = s * 0.125f;
        }
        float m = sc;
        #pragma unroll
        for (int off = 32; off; off >>= 1) m = fmaxf(m, __shfl_xor(m, off, 64));
        float p = (tid <= t) ? expf(sc - m) : 0.f;
        float sum = p;
        #pragma unroll
        for (int off = 32; off; off >>= 1) sum += __shfl_xor(sum, off, 64);
        p /= sum;
        probs[tid] = p;
        __syncthreads();

        float o = 0.f;
        for (int s = 0; s <= t; ++s) o = fmaf(probs[s], vs[s][tid], o);
        out[(size_t)(b * T + t) * 256 + h * 64 + tid] = f2bf(o);
        __syncthreads();
    }
}

// ---------------------------------------------------------------- row L2 normalize (width 256) -> bf16
__global__ __launch_bounds__(256)
void l2norm_kernel(const float* __restrict__ X, bfu* __restrict__ Y)
{
    __shared__ float sbuf[4];
    const int row = blockIdx.x;
    const float v = X[(size_t)row * 256 + threadIdx.x];
    float s = v * v;
    #pragma unroll
    for (int off = 32; off; off >>= 1) s += __shfl_down(s, off, 64);
    const int lane = threadIdx.x & 63, wid = threadIdx.x >> 6;
    if (lane == 0) sbuf[wid] = s;
    __syncthreads();
    float n = sqrtf(sbuf[0] + sbuf[1] + sbuf[2] + sbuf[3]);
    n = fmaxf(n, 1e-12f);
    Y[(size_t)row * 256 + threadIdx.x] = f2bf(v / n);
}

// ---------------------------------------------------------------- driver
extern "C" void kernel_launch(void* const* d_in, const int* in_sizes, int n_in,
                              void* d_out, int out_size, void* d_ws, size_t ws_size,
                              hipStream_t stream)
{
    const float* x         = (const float*)d_in[0];
    const float* p1_w      = (const float*)d_in[1];
    const float* p1_b      = (const float*)d_in[2];
    const float* pln1_w    = (const float*)d_in[3];
    const float* pln1_b    = (const float*)d_in[4];
    const float* p2_w      = (const float*)d_in[5];
    const float* pln2_w    = (const float*)d_in[6];
    const float* pln2_b    = (const float*)d_in[7];
    const float* in_proj_w = (const float*)d_in[8];
    const float* in_proj_b = (const float*)d_in[9];
    const float* out_proj_w= (const float*)d_in[10];
    const float* out_proj_b= (const float*)d_in[11];
    const float* ln1_w     = (const float*)d_in[12];
    const float* ln1_b     = (const float*)d_in[13];
    const float* lin1_w    = (const float*)d_in[14];
    const float* lin1_b    = (const float*)d_in[15];
    const float* lin2_w    = (const float*)d_in[16];
    const float* lin2_b    = (const float*)d_in[17];
    const float* ln2_w     = (const float*)d_in[18];
    const float* ln2_b     = (const float*)d_in[19];
    const float* head_w    = (const float*)d_in[20];

    const int B = 2048, T = 20, E = 256, HID = 1024, CLS = 1000, L = 2, H = 4;
    const int M = B * T;   // 40960
    const int D = 2048;

    // ---- workspace carve-up (~238 MB) ----
    char* p = (char*)d_ws;
    float* h      = (float*)p;  p += (size_t)M * E * 4;        // fp32 residual state
    float* ffout  = (float*)p;  p += (size_t)M * E * 4;        // ff2 output fp32
    bfu*   hb     = (bfu*)p;    p += (size_t)M * E * 2;        // bf16 copy of h
    bfu*   h1b    = (bfu*)p;    p += (size_t)M * HID * 2;      // proj hidden / FF hidden bf16
    bfu*   abf    = (bfu*)p;    p += (size_t)M * E * 2;        // attention out bf16
    bfu*   wblk   = (bfu*)p;    p += (size_t)3932160 * 2;      // 6 bf16 weight buffers, contiguous
    bfu*   wnb    = (bfu*)p;    p += (size_t)1024 * E * 2;     // normalized head_w, padded to 1024 rows

    bfu* p1wb  = wblk;
    bfu* p2wb  = p1wb  + (size_t)HID * D;
    bfu* qkvwb = p2wb  + (size_t)E * HID;
    bfu* outwb = qkvwb + (size_t)L * 3 * E * E;
    bfu* l1wb  = outwb + (size_t)L * E * E;
    bfu* l2wb  = l1wb  + (size_t)L * 4 * E * E;

    float* out   = (float*)d_out;
    bfu*   qkvb  = (bfu*)d_out;        // [M,768] bf16 scratch inside d_out
    float* attnp = (float*)d_out;      // [M,256] fp32 scratch (qkvb dead by then)

    // ---- weights -> bf16 (one fused kernel) ----
    cvt6_kernel<<<2048, 256, 0, stream>>>(p1_w, p2_w, in_proj_w, out_proj_w, lin1_w, lin2_w, wblk);

    // ---- projector ----
    mfma_gemm<true, false, true><<<dim3(8 * (M/128)), 256, 0, stream>>>(
        x, p1wb, p1_b, h1b, M, HID, D, 1.f, 8);
    ln_kernel<4, true, false, false, true><<<M, 256, 0, stream>>>(
        h1b, nullptr, pln1_w, pln1_b, nullptr, h1b, T);
    mfma_gemm<false, false, false><<<dim3(2 * (M/128)), 256, 0, stream>>>(
        h1b, p2wb, nullptr, h, M, E, HID, 1.f, 2);
    ln_kernel<1, false, true, false, false><<<M, 256, 0, stream>>>(
        h, nullptr, pln2_w, pln2_b, h, hb, T);

    // ---- transformer layers (post-norm) ----
    for (int l = 0; l < L; ++l) {
        mfma_gemm<false, false, true><<<dim3(6 * (M/128)), 256, 0, stream>>>(
            hb, qkvwb + (size_t)l * 3*E*E, in_proj_b + (size_t)l * 3*E, qkvb, M, 3*E, E, 1.f, 6);
        attn_kernel<<<B * H, 64, 0, stream>>>(qkvb, abf, B, T, H);
        mfma_gemm<false, false, false><<<dim3(2 * (M/128)), 256, 0, stream>>>(
            abf, outwb + (size_t)l * E*E, out_proj_b + (size_t)l * E, attnp, M, E, E, 1.f, 2);
        ln_kernel<1, false, false, true, false><<<M, 256, 0, stream>>>(
            h, attnp, ln1_w + (size_t)l * E, ln1_b + (size_t)l * E, h, hb, T);
        mfma_gemm<false, true, true><<<dim3(8 * (M/128)), 256, 0, stream>>>(
            hb, l1wb + (size_t)l * 4*E*E, lin1_b + (size_t)l * 4*E, h1b, M, HID, E, 1.f, 8);
        mfma_gemm<false, false, false><<<dim3(2 * (M/128)), 256, 0, stream>>>(
            h1b, l2wb + (size_t)l * E*4*E, lin2_b + (size_t)l * E, ffout, M, E, HID, 1.f, 2);
        ln_kernel<1, false, false, true, false><<<M, 256, 0, stream>>>(
            h, ffout, ln2_w + (size_t)l * E, ln2_b + (size_t)l * E, h, hb, T);
    }

    // ---- head ----
    l2norm_kernel<<<M, 256, 0, stream>>>(h, hb);           // flat = bf16(normalize(h))
    l2norm_kernel<<<CLS, 256, 0, stream>>>(head_w, wnb);   // wn  = bf16(normalize(head_w)); pad rows junk (safe)
    mfma_gemm<false, false, false><<<dim3(8 * (M/128)), 256, 0, stream>>>(
        hb, wnb, nullptr, out, M, CLS, E, 10.f, 8);
}

// Round 4
// 1391.197 us; speedup vs baseline: 3.7699x; 1.0330x over previous
//
#include <hip/hip_runtime.h>
#include <math.h>

#define CDIV(a,b) (((a)+(b)-1)/(b))

typedef unsigned short bfu;                                   // bf16 bits
typedef short   s16x8 __attribute__((ext_vector_type(8)));    // MFMA A/B frag (8 bf16)
typedef float   f32x4 __attribute__((ext_vector_type(4)));    // MFMA C/D frag

// async global->LDS, 16B per lane. LDS dst must be wave-uniform; HW writes base+lane*16.
#define GLOAD16(gp, lp) __builtin_amdgcn_global_load_lds( \
    (const __attribute__((address_space(1))) void*)(gp),  \
    (__attribute__((address_space(3))) void*)(lp), 16, 0, 0)

// ---------------------------------------------------------------- helpers
static __device__ __forceinline__ float gelu_exact(float x) {
    return 0.5f * x * (1.0f + erff(x * 0.7071067811865475f));
}
static __device__ __forceinline__ bfu f2bf(float x) {         // RNE f32->bf16
    unsigned int u = __float_as_uint(x);
    unsigned int r = u + 0x7fffu + ((u >> 16) & 1u);
    return (bfu)(r >> 16);
}
static __device__ __forceinline__ float bf2f(bfu b) {
    return __uint_as_float(((unsigned int)b) << 16);
}

static __device__ __forceinline__ float block_sum_256(float v, float* sbuf) {
    #pragma unroll
    for (int off = 32; off; off >>= 1) v += __shfl_down(v, off, 64);
    const int lane = threadIdx.x & 63;
    const int wid  = threadIdx.x >> 6;
    __syncthreads();
    if (lane == 0) sbuf[wid] = v;
    __syncthreads();
    return sbuf[0] + sbuf[1] + sbuf[2] + sbuf[3];
}

// ---------------------------------------------------------------- fp32 -> bf16 convert (grid-stride)
__global__ __launch_bounds__(256)
void cvt_kernel(const float* __restrict__ in, bfu* __restrict__ out, int n4)
{
    int i = blockIdx.x * 256 + threadIdx.x;
    const int stride = gridDim.x * 256;
    for (; i < n4; i += stride) {
        float4 f = ((const float4*)in)[i];
        ushort4 o;
        o.x = f2bf(f.x); o.y = f2bf(f.y); o.z = f2bf(f.z); o.w = f2bf(f.w);
        ((ushort4*)out)[i] = o;
    }
}

// ---------------------------------------------------------------- fused weight convert (6 regions)
__global__ __launch_bounds__(256)
void cvt6_kernel(const float* __restrict__ s0, const float* __restrict__ s1,
                 const float* __restrict__ s2, const float* __restrict__ s3,
                 const float* __restrict__ s4, const float* __restrict__ s5,
                 bfu* __restrict__ dst)
{
    const int c0 = 524288;           // p1_w  1024*2048/4
    const int c1 = c0 + 65536;       // p2_w  256*1024/4
    const int c2 = c1 + 98304;       // in_proj 2*768*256/4
    const int c3 = c2 + 32768;       // out_proj 2*256*256/4
    const int c4 = c3 + 131072;      // lin1 2*1024*256/4
    const int c5 = c4 + 131072;      // lin2 2*256*1024/4
    int i = blockIdx.x * 256 + threadIdx.x;
    const int stride = gridDim.x * 256;
    for (; i < c5; i += stride) {
        const float* s; int base;
        if      (i < c0) { s = s0; base = 0;  }
        else if (i < c1) { s = s1; base = c0; }
        else if (i < c2) { s = s2; base = c1; }
        else if (i < c3) { s = s3; base = c2; }
        else if (i < c4) { s = s4; base = c3; }
        else             { s = s5; base = c4; }
        float4 f = ((const float4*)s)[i - base];
        ushort4 o;
        o.x = f2bf(f.x); o.y = f2bf(f.y); o.z = f2bf(f.z); o.w = f2bf(f.w);
        ((ushort4*)dst)[i] = o;
    }
}

// ---------------------------------------------------------------- MFMA GEMM (m97 structure, all-bf16)
// C[M,N] = scale * epi(A[M,K] @ W[N,K]^T + bias)
// 128x128 tile, BK=32, 256 threads (4 waves, 4x4 frags of 16x16x32 each).
// Staging: global_load_lds dwordx4 into linear LDS [128][32] bf16 (64B rows).
// XCD-chunk swizzle on 1-D grid (requires nwg%8==0 when enabled).
// M%128==0, K%32==0; W may have pad rows up to tile edge (never stored).
template<bool GELU_EP, bool OUT_BF16>
__global__ __launch_bounds__(256)
void mfma_gemm(const bfu* __restrict__ A, const bfu* __restrict__ W,
               const float* __restrict__ bias, void* __restrict__ Cv,
               int M, int N, int K, float scale, int ntx)
{
    __shared__ bfu As[128 * 32];
    __shared__ bfu Ws[128 * 32];

    const int tid = threadIdx.x;
    const int nwg = gridDim.x;
    const int lid = (nwg & 7) ? (int)blockIdx.x
                              : ((int)blockIdx.x & 7) * (nwg >> 3) + ((int)blockIdx.x >> 3);
    const int row0 = (lid / ntx) * 128;
    const int col0 = (lid % ntx) * 128;

    const int lane = tid & 63;
    const int wave = tid >> 6;
    const int wm = (wave >> 1) * 64;
    const int wn = (wave & 1) * 64;
    const int fr = lane & 15;
    const int fk = (lane >> 4) * 8;

    // gload addressing: one wave-load covers 16 rows x 32 k (1KB). lane: row=l>>2, k=(l&3)*8.
    const int lrow = lane >> 2;
    const int lk   = (lane & 3) * 8;
    const bfu* al0 = A + (size_t)(row0 + wave * 32 + lrow) * K + lk;
    const bfu* al1 = al0 + (size_t)16 * K;
    const bfu* wl0 = W + (size_t)(col0 + wave * 32 + lrow) * K + lk;
    const bfu* wl1 = wl0 + (size_t)16 * K;
    bfu* ad0 = &As[(wave * 2    ) * 512];
    bfu* ad1 = &As[(wave * 2 + 1) * 512];
    bfu* wd0 = &Ws[(wave * 2    ) * 512];
    bfu* wd1 = &Ws[(wave * 2 + 1) * 512];

    f32x4 acc[4][4];
    #pragma unroll
    for (int i = 0; i < 4; ++i)
        #pragma unroll
        for (int j = 0; j < 4; ++j) acc[i][j] = (f32x4)0.f;

    for (int k0 = 0; k0 < K; k0 += 32) {
        GLOAD16(al0 + k0, ad0);
        GLOAD16(al1 + k0, ad1);
        GLOAD16(wl0 + k0, wd0);
        GLOAD16(wl1 + k0, wd1);
        __syncthreads();

        s16x8 af[4], wf[4];
        #pragma unroll
        for (int i = 0; i < 4; ++i) af[i] = *(const s16x8*)&As[(wm + 16*i + fr) * 32 + fk];
        #pragma unroll
        for (int j = 0; j < 4; ++j) wf[j] = *(const s16x8*)&Ws[(wn + 16*j + fr) * 32 + fk];

        #pragma unroll
        for (int i = 0; i < 4; ++i)
            #pragma unroll
            for (int j = 0; j < 4; ++j)
                acc[i][j] = __builtin_amdgcn_mfma_f32_16x16x32_bf16(af[i], wf[j], acc[i][j], 0, 0, 0);
        __syncthreads();
    }

    // epilogue: D row = 4*(lane>>4)+rr, col = lane&15 within each 16x16 frag
    #pragma unroll
    for (int i = 0; i < 4; ++i) {
        const int r = row0 + wm + 16 * i + (lane >> 4) * 4;
        #pragma unroll
        for (int j = 0; j < 4; ++j) {
            const int c = col0 + wn + 16 * j + fr;
            if (c < N) {
                const float bsum = bias ? bias[c] : 0.f;
                #pragma unroll
                for (int rr = 0; rr < 4; ++rr) {
                    float v = acc[i][j][rr] + bsum;
                    if (GELU_EP) v = gelu_exact(v);
                    v *= scale;
                    if (OUT_BF16) ((bfu*)Cv)[(size_t)(r + rr) * N + c] = f2bf(v);
                    else          ((float*)Cv)[(size_t)(r + rr) * N + c] = v;
                }
            }
        }
    }
}

// ---------------------------------------------------------------- LayerNorm variants
template<int VPT, bool GELU_EP, bool ADD_PE, bool RES, bool IN_BF16>
__global__ __launch_bounds__(256)
void ln_kernel(const void* __restrict__ Xv, const float* __restrict__ R,
               const float* __restrict__ w, const float* __restrict__ b,
               float* __restrict__ Yf, bfu* __restrict__ Yb, int T)
{
    const int W = VPT * 256;
    __shared__ float sbuf[4];
    const int row = blockIdx.x;

    float v[VPT];
    if (IN_BF16) {
        const bfu* xr = (const bfu*)Xv + (size_t)row * W;
        if (VPT == 4) {
            ushort4 t4 = *(const ushort4*)(xr + threadIdx.x * 4);
            v[0] = bf2f(t4.x); v[1] = bf2f(t4.y); v[2] = bf2f(t4.z); v[3] = bf2f(t4.w);
        } else {
            v[0] = bf2f(xr[threadIdx.x]);
        }
    } else {
        const float* xr = (const float*)Xv + (size_t)row * W;
        if (VPT == 4) {
            float4 t4 = *(const float4*)(xr + threadIdx.x * 4);
            v[0] = t4.x; v[1] = t4.y; v[2] = t4.z; v[3] = t4.w;
        } else {
            v[0] = xr[threadIdx.x];
        }
    }
    if (RES) {
        #pragma unroll
        for (int j = 0; j < VPT; ++j)
            v[j] += R[(size_t)row * W + ((VPT == 4) ? threadIdx.x * 4 + j : (int)threadIdx.x)];
    }

    float s = 0.f;
    #pragma unroll
    for (int j = 0; j < VPT; ++j) s += v[j];
    const float mean = block_sum_256(s, sbuf) / (float)W;

    float q = 0.f;
    #pragma unroll
    for (int j = 0; j < VPT; ++j) { float d = v[j] - mean; q += d * d; }
    const float var  = block_sum_256(q, sbuf) / (float)W;
    const float rstd = rsqrtf(var + 1e-6f);

    #pragma unroll
    for (int j = 0; j < VPT; ++j) {
        const int c = (VPT == 4) ? (threadIdx.x * 4 + j) : (int)threadIdx.x;
        float y = (v[j] - mean) * rstd * w[c] + b[c];
        if (GELU_EP) y = gelu_exact(y);
        if (ADD_PE) {
            const int t = row % T;
            const float cc  = (float)(c & ~1);
            const float div = expf(cc * (-9.210340371976184f / 256.0f));
            const float ang = (float)t * div;
            y += (c & 1) ? cosf(ang) : sinf(ang);
        }
        if (Yf) Yf[(size_t)row * W + c] = y;
        if (Yb) Yb[(size_t)row * W + c] = f2bf(y);
    }
}

// ---------------------------------------------------------------- causal attention, T=20, hd=64
// one wave per (batch, head). qkv bf16 [B*T,768] -> out bf16 [B*T,256]
__global__ __launch_bounds__(64)
void attn_kernel(const bfu* __restrict__ qkv, bfu* __restrict__ out,
                 int B, int T, int H)
{
    __shared__ float qs[20][65];
    __shared__ float ks[20][65];
    __shared__ float vs[20][65];
    __shared__ float probs[64];

    const int blk = blockIdx.x;
    const int b = blk / H;
    const int h = blk % H;
    const int tid = threadIdx.x;

    for (int t = 0; t < T; ++t) {
        const bfu* base = qkv + (size_t)(b * T + t) * 768 + h * 64 + tid;
        qs[t][tid] = bf2f(base[0]);
        ks[t][tid] = bf2f(base[256]);
        vs[t][tid] = bf2f(base[512]);
    }
    __syncthreads();

    for (int t = 0; t < T; ++t) {
        float sc = -INFINITY;
        if (tid <= t) {
            float s = 0.f;
            #pragma unroll
            for (int d = 0; d < 64; ++d) s = fmaf(qs[t][d], ks[tid][d], s);
            sc = s * 0.125f;
        }
        float m = sc;
        #pragma unroll
        for (int off = 32; off; off >>= 1) m = fmaxf(m, __shfl_xor(m, off, 64));
        float p = (tid <= t) ? expf(sc - m) : 0.f;
        float sum = p;
        #pragma unroll
        for (int off = 32; off; off >>= 1) sum += __shfl_xor(sum, off, 64);
        p /= sum;
        probs[tid] = p;
        __syncthreads();

        float o = 0.f;
        for (int s = 0; s <= t; ++s) o = fmaf(probs[s], vs[s][tid], o);
        out[(size_t)(b * T + t) * 256 + h * 64 + tid] = f2bf(o);
        __syncthreads();
    }
}

// ---------------------------------------------------------------- row L2 normalize (width 256) -> bf16
__global__ __launch_bounds__(256)
void l2norm_kernel(const float* __restrict__ X, bfu* __restrict__ Y)
{
    __shared__ float sbuf[4];
    const int row = blockIdx.x;
    const float v = X[(size_t)row * 256 + threadIdx.x];
    float s = v * v;
    #pragma unroll
    for (int off = 32; off; off >>= 1) s += __shfl_down(s, off, 64);
    const int lane = threadIdx.x & 63, wid = threadIdx.x >> 6;
    if (lane == 0) sbuf[wid] = s;
    __syncthreads();
    float n = sqrtf(sbuf[0] + sbuf[1] + sbuf[2] + sbuf[3]);
    n = fmaxf(n, 1e-12f);
    Y[(size_t)row * 256 + threadIdx.x] = f2bf(v / n);
}

// ---------------------------------------------------------------- driver
extern "C" void kernel_launch(void* const* d_in, const int* in_sizes, int n_in,
                              void* d_out, int out_size, void* d_ws, size_t ws_size,
                              hipStream_t stream)
{
    const float* x         = (const float*)d_in[0];
    const float* p1_w      = (const float*)d_in[1];
    const float* p1_b      = (const float*)d_in[2];
    const float* pln1_w    = (const float*)d_in[3];
    const float* pln1_b    = (const float*)d_in[4];
    const float* p2_w      = (const float*)d_in[5];
    const float* pln2_w    = (const float*)d_in[6];
    const float* pln2_b    = (const float*)d_in[7];
    const float* in_proj_w = (const float*)d_in[8];
    const float* in_proj_b = (const float*)d_in[9];
    const float* out_proj_w= (const float*)d_in[10];
    const float* out_proj_b= (const float*)d_in[11];
    const float* ln1_w     = (const float*)d_in[12];
    const float* ln1_b     = (const float*)d_in[13];
    const float* lin1_w    = (const float*)d_in[14];
    const float* lin1_b    = (const float*)d_in[15];
    const float* lin2_w    = (const float*)d_in[16];
    const float* lin2_b    = (const float*)d_in[17];
    const float* ln2_w     = (const float*)d_in[18];
    const float* ln2_b     = (const float*)d_in[19];
    const float* head_w    = (const float*)d_in[20];

    const int B = 2048, T = 20, E = 256, HID = 1024, CLS = 1000, L = 2, H = 4;
    const int M = B * T;   // 40960
    const int D = 2048;

    // ---- workspace carve-up ----
    // xb [M*D bf16, 168MB] is dead after proj1; post-proj1 buffers alias its front.
    char* p = (char*)d_ws;
    bfu*   xb     = (bfu*)p;    p += (size_t)M * D * 2;        // bf16 copy of x
    bfu*   h1b    = (bfu*)p;    p += (size_t)M * HID * 2;      // proj hidden / FF hidden bf16
    bfu*   wblk   = (bfu*)p;    p += (size_t)3932160 * 2;      // 6 bf16 weight buffers, contiguous
    bfu*   wnb    = (bfu*)p;    p += (size_t)1024 * E * 2;     // normalized head_w, padded rows

    char* q = (char*)xb;       // aliases xb (used only after proj1 completes)
    float* h      = (float*)q;  q += (size_t)M * E * 4;        // fp32 residual state
    float* ffout  = (float*)q;  q += (size_t)M * E * 4;        // ff2 output fp32
    bfu*   hb     = (bfu*)q;    q += (size_t)M * E * 2;        // bf16 copy of h
    bfu*   abf    = (bfu*)q;    q += (size_t)M * E * 2;        // attention out bf16

    bfu* p1wb  = wblk;
    bfu* p2wb  = p1wb  + (size_t)HID * D;
    bfu* qkvwb = p2wb  + (size_t)E * HID;
    bfu* outwb = qkvwb + (size_t)L * 3 * E * E;
    bfu* l1wb  = outwb + (size_t)L * E * E;
    bfu* l2wb  = l1wb  + (size_t)L * 4 * E * E;

    float* out   = (float*)d_out;
    bfu*   qkvb  = (bfu*)d_out;        // [M,768] bf16 scratch inside d_out
    float* attnp = (float*)d_out;      // [M,256] fp32 scratch (qkvb dead by then)

    // ---- convert inputs/weights to bf16 ----
    cvt_kernel<<<2048, 256, 0, stream>>>(x, xb, M * D / 4);
    cvt6_kernel<<<2048, 256, 0, stream>>>(p1_w, p2_w, in_proj_w, out_proj_w, lin1_w, lin2_w, wblk);

    // ---- projector ----
    mfma_gemm<false, true><<<dim3(8 * (M/128)), 256, 0, stream>>>(
        xb, p1wb, p1_b, h1b, M, HID, D, 1.f, 8);
    ln_kernel<4, true, false, false, true><<<M, 256, 0, stream>>>(
        h1b, nullptr, pln1_w, pln1_b, nullptr, h1b, T);
    mfma_gemm<false, false><<<dim3(2 * (M/128)), 256, 0, stream>>>(
        h1b, p2wb, nullptr, h, M, E, HID, 1.f, 2);
    ln_kernel<1, false, true, false, false><<<M, 256, 0, stream>>>(
        h, nullptr, pln2_w, pln2_b, h, hb, T);

    // ---- transformer layers (post-norm) ----
    for (int l = 0; l < L; ++l) {
        mfma_gemm<false, true><<<dim3(6 * (M/128)), 256, 0, stream>>>(
            hb, qkvwb + (size_t)l * 3*E*E, in_proj_b + (size_t)l * 3*E, qkvb, M, 3*E, E, 1.f, 6);
        attn_kernel<<<B * H, 64, 0, stream>>>(qkvb, abf, B, T, H);
        mfma_gemm<false, false><<<dim3(2 * (M/128)), 256, 0, stream>>>(
            abf, outwb + (size_t)l * E*E, out_proj_b + (size_t)l * E, attnp, M, E, E, 1.f, 2);
        ln_kernel<1, false, false, true, false><<<M, 256, 0, stream>>>(
            h, attnp, ln1_w + (size_t)l * E, ln1_b + (size_t)l * E, h, hb, T);
        mfma_gemm<true, true><<<dim3(8 * (M/128)), 256, 0, stream>>>(
            hb, l1wb + (size_t)l * 4*E*E, lin1_b + (size_t)l * 4*E, h1b, M, HID, E, 1.f, 8);
        mfma_gemm<false, false><<<dim3(2 * (M/128)), 256, 0, stream>>>(
            h1b, l2wb + (size_t)l * E*4*E, lin2_b + (size_t)l * E, ffout, M, E, HID, 1.f, 2);
        ln_kernel<1, false, false, true, false><<<M, 256, 0, stream>>>(
            h, ffout, ln2_w + (size_t)l * E, ln2_b + (size_t)l * E, h, hb, T);
    }

    // ---- head ----
    l2norm_kernel<<<M, 256, 0, stream>>>(h, hb);           // flat = bf16(normalize(h))
    l2norm_kernel<<<CLS, 256, 0, stream>>>(head_w, wnb);   // wn = bf16(normalize(head_w)); pad rows junk (safe)
    mfma_gemm<false, false><<<dim3(8 * (M/128)), 256, 0, stream>>>(
        hb, wnb, nullptr, out, M, CLS, E, 10.f, 8);
}